// Round 1
// baseline (1038.865 us; speedup 1.0000x reference)
//
#include <hip/hip_runtime.h>

#define NN 50000
#define NG 256
#define CF 108
#define MD 88
#define OD 100
#define YS 192   // Y row stride: [0,88)=yl, [88,176)=yr(+bias), [176,192) pad

// ---------------- CSR build ----------------

__global__ void count_deg_kernel(const int* __restrict__ edge, int E, int* __restrict__ deg) {
    int e = blockIdx.x * blockDim.x + threadIdx.x;
    if (e >= E) return;
    atomicAdd(&deg[edge[E + e]], 1);   // dst row
}

// single wave (64 lanes), shuffle-based exclusive scan, no barriers
__global__ void scan_kernel(const int* __restrict__ deg, int* __restrict__ off,
                            int* __restrict__ cursor, int n) {
    int lane = threadIdx.x;
    int carry = 0;
    if (lane == 0) off[0] = 0;
    for (int base = 0; base < n; base += 64) {
        int i = base + lane;
        int v = (i < n) ? deg[i] : 0;
        int incl = v;
        #pragma unroll
        for (int s = 1; s < 64; s <<= 1) {
            int t = __shfl_up(incl, s, 64);
            if (lane >= s) incl += t;
        }
        if (i < n) {
            off[i + 1]  = carry + incl;
            cursor[i]   = carry + incl - v;   // exclusive prefix
        }
        carry += __shfl(incl, 63, 64);
    }
}

__global__ void fill_csr_kernel(const int* __restrict__ edge, int E,
                                int* __restrict__ cursor, int* __restrict__ csr_src) {
    int e = blockIdx.x * blockDim.x + threadIdx.x;
    if (e >= E) return;
    int dst = edge[E + e];
    int pos = atomicAdd(&cursor[dst], 1);
    csr_src[pos] = edge[e];   // store src node id
}

// ---------------- weights: combined [din][192] = [Wl | Wr | 0pad] ----------------

__global__ void build_wc_kernel(const float* __restrict__ Wl, const float* __restrict__ Wr,
                                float* __restrict__ Wc, int din) {
    int idx = blockIdx.x * blockDim.x + threadIdx.x;
    if (idx >= din * YS) return;
    int k = idx / YS, c = idx % YS;
    float v = 0.f;
    if (c < MD)            v = Wl[k * MD + c];
    else if (c < 2 * MD)   v = Wr[k * MD + (c - MD)];
    Wc[idx] = v;
}

// ---------------- GEMM: Y[N,192] = A[N,DIN] @ Wc[DIN,192]  (+bias on cols 88..175) ----------------
// block = 256 threads, tile = 64 rows x 192 cols, thread = 4 rows x 12 cols

template <int DIN>
__global__ __launch_bounds__(256) void gemm_kernel(const float* __restrict__ A,
                                                   const float* __restrict__ Wc,
                                                   const float* __restrict__ bias,
                                                   float* __restrict__ Y, int N) {
    __shared__ float w[64 * YS];   // 48 KiB
    const int tid  = threadIdx.x;
    const int col0 = (tid & 15) * 12;
    const int rbase = blockIdx.x * 64 + (tid >> 4) * 4;

    const float* a0 = A + (size_t)min(rbase + 0, N - 1) * DIN;
    const float* a1 = A + (size_t)min(rbase + 1, N - 1) * DIN;
    const float* a2 = A + (size_t)min(rbase + 2, N - 1) * DIN;
    const float* a3 = A + (size_t)min(rbase + 3, N - 1) * DIN;

    float acc[4][12];
    #pragma unroll
    for (int r = 0; r < 4; ++r)
        #pragma unroll
        for (int j = 0; j < 12; ++j) acc[r][j] = 0.f;

    for (int kc = 0; kc < DIN; kc += 64) {
        const int klen = (DIN - kc < 64) ? (DIN - kc) : 64;
        const int nf4 = klen * (YS / 4);
        const float4* src = (const float4*)(Wc + kc * YS);
        for (int i = tid; i < nf4; i += 256) ((float4*)w)[i] = src[i];
        __syncthreads();

        for (int k = 0; k < klen; ++k) {
            const float* wr = &w[k * YS + col0];
            float wv[12];
            *(float4*)&wv[0] = *(const float4*)(wr);
            *(float4*)&wv[4] = *(const float4*)(wr + 4);
            *(float4*)&wv[8] = *(const float4*)(wr + 8);
            const int kk = kc + k;
            float av[4] = { a0[kk], a1[kk], a2[kk], a3[kk] };
            #pragma unroll
            for (int r = 0; r < 4; ++r)
                #pragma unroll
                for (int j = 0; j < 12; ++j)
                    acc[r][j] = fmaf(av[r], wv[j], acc[r][j]);
        }
        __syncthreads();
    }

    #pragma unroll
    for (int r = 0; r < 4; ++r) {
        const int row = rbase + r;
        if (row >= N) continue;
        float outv[12];
        #pragma unroll
        for (int j = 0; j < 12; ++j) {
            const int c = col0 + j;
            float v = acc[r][j];
            if (c >= MD && c < 2 * MD) v += bias[c - MD];
            outv[j] = v;
        }
        float* yp = Y + (size_t)row * YS + col0;
        *(float4*)(yp)     = *(float4*)&outv[0];
        *(float4*)(yp + 4) = *(float4*)&outv[4];
        *(float4*)(yp + 8) = *(float4*)&outv[8];
    }
}

// ---------------- fused aggregate: h = relu( (sum_{src in N(n)} yl[src]) / max(deg,1) + yr[n] ) ----------------
// one thread per (node, feature)

__global__ void agg_kernel(const float* __restrict__ Y, const int* __restrict__ off,
                           const int* __restrict__ csr, float* __restrict__ h, int N) {
    int idx = blockIdx.x * blockDim.x + threadIdx.x;
    if (idx >= N * MD) return;
    int n = idx / MD;
    int f = idx - n * MD;
    int s = off[n], e = off[n + 1];
    float acc = 0.f;
    for (int i = s; i < e; ++i) {
        acc += Y[(size_t)csr[i] * YS + f];
    }
    float d = (float)((e - s) > 1 ? (e - s) : 1);
    float v = acc / d + Y[(size_t)n * YS + MD + f];
    h[(size_t)n * MD + f] = fmaxf(v, 0.f);
}

// ---------------- pooling ----------------

__global__ void gstarts_kernel(const int* __restrict__ batch, int* __restrict__ gstart, int n) {
    int i = blockIdx.x * blockDim.x + threadIdx.x;
    if (i >= n) return;
    int b = batch[i];
    int prev = (i == 0) ? -1 : batch[i - 1];
    for (int g = prev + 1; g <= b; ++g) gstart[g] = i;
    if (i == n - 1) {
        for (int g = b + 1; g <= NG; ++g) gstart[g] = n;
    }
}

__global__ void pool_kernel(const float* __restrict__ h, const int* __restrict__ gstart,
                            float* __restrict__ pooled) {
    int g = blockIdx.x;
    int f = threadIdx.x;
    if (f >= MD) return;
    int s = gstart[g], e = gstart[g + 1];
    float acc = 0.f;
    for (int n = s; n < e; ++n) acc += h[(size_t)n * MD + f];
    pooled[g * MD + f] = acc;
}

__global__ void final_kernel(const float* __restrict__ pooled, const float* __restrict__ Wlin,
                             const float* __restrict__ blin, float* __restrict__ out) {
    int idx = blockIdx.x * blockDim.x + threadIdx.x;
    if (idx >= NG * OD) return;
    int g = idx / OD, o = idx - (idx / OD) * OD;
    float acc = blin[o];
    for (int f = 0; f < MD; ++f)
        acc = fmaf(pooled[g * MD + f], Wlin[f * OD + o], acc);
    out[idx] = acc;
}

// ---------------- launch ----------------

extern "C" void kernel_launch(void* const* d_in, const int* in_sizes, int n_in,
                              void* d_out, int out_size, void* d_ws, size_t ws_size,
                              hipStream_t stream) {
    const float* x     = (const float*)d_in[0];
    const int*   edge  = (const int*)d_in[1];
    const int*   batch = (const int*)d_in[2];
    const float* W1l = (const float*)d_in[3];
    const float* W1r = (const float*)d_in[4];
    const float* b1  = (const float*)d_in[5];
    const float* W2l = (const float*)d_in[6];
    const float* W2r = (const float*)d_in[7];
    const float* b2  = (const float*)d_in[8];
    const float* W3l = (const float*)d_in[9];
    const float* W3r = (const float*)d_in[10];
    const float* b3  = (const float*)d_in[11];
    const float* Wlin = (const float*)d_in[12];
    const float* blin = (const float*)d_in[13];
    float* out = (float*)d_out;

    const int N = in_sizes[0] / CF;   // 50000
    const int E = in_sizes[1] / 2;    // 800000

    char* ws = (char*)d_ws;
    auto alloc = [&](size_t bytes) -> void* {
        void* p = (void*)ws;
        ws += (bytes + 255) & ~(size_t)255;
        return p;
    };
    int*   deg    = (int*)alloc((size_t)N * 4);
    int*   off    = (int*)alloc((size_t)(N + 1) * 4);
    int*   cursor = (int*)alloc((size_t)N * 4);
    int*   csr    = (int*)alloc((size_t)E * 4);
    int*   gstart = (int*)alloc((size_t)(NG + 1) * 4);
    float* Wc     = (float*)alloc((size_t)CF * YS * 4);
    float* Y      = (float*)alloc((size_t)N * YS * 4);
    float* h      = (float*)alloc((size_t)N * MD * 4);
    float* pooled = (float*)alloc((size_t)NG * MD * 4);

    hipMemsetAsync(deg, 0, (size_t)N * 4, stream);
    count_deg_kernel<<<(E + 255) / 256, 256, 0, stream>>>(edge, E, deg);
    scan_kernel<<<1, 64, 0, stream>>>(deg, off, cursor, N);
    fill_csr_kernel<<<(E + 255) / 256, 256, 0, stream>>>(edge, E, cursor, csr);

    const int gemm_blocks = (N + 63) / 64;
    const int agg_blocks  = (N * MD + 255) / 256;

    // layer 1
    build_wc_kernel<<<(CF * YS + 255) / 256, 256, 0, stream>>>(W1l, W1r, Wc, CF);
    gemm_kernel<CF><<<gemm_blocks, 256, 0, stream>>>(x, Wc, b1, Y, N);
    agg_kernel<<<agg_blocks, 256, 0, stream>>>(Y, off, csr, h, N);

    // layer 2
    build_wc_kernel<<<(MD * YS + 255) / 256, 256, 0, stream>>>(W2l, W2r, Wc, MD);
    gemm_kernel<MD><<<gemm_blocks, 256, 0, stream>>>(h, Wc, b2, Y, N);
    agg_kernel<<<agg_blocks, 256, 0, stream>>>(Y, off, csr, h, N);

    // layer 3
    build_wc_kernel<<<(MD * YS + 255) / 256, 256, 0, stream>>>(W3l, W3r, Wc, MD);
    gemm_kernel<MD><<<gemm_blocks, 256, 0, stream>>>(h, Wc, b3, Y, N);
    agg_kernel<<<agg_blocks, 256, 0, stream>>>(Y, off, csr, h, N);

    // pool + classifier
    gstarts_kernel<<<(N + 255) / 256, 256, 0, stream>>>(batch, gstart, N);
    pool_kernel<<<NG, 128, 0, stream>>>(h, gstart, pooled);
    final_kernel<<<(NG * OD + 255) / 256, 256, 0, stream>>>(pooled, Wlin, blin, out);
}

// Round 2
// 667.209 us; speedup vs baseline: 1.5570x; 1.5570x over previous
//
#include <hip/hip_runtime.h>

#define NN 50000
#define NG 256
#define CF 108
#define MD 88
#define OD 100
#define YS 192   // Y row stride: [0,88)=yl, [88,176)=yr(+bias), [176,192) pad

// ---------------- CSR build ----------------

__global__ void count_deg_kernel(const int* __restrict__ edge, int E, int* __restrict__ deg) {
    int e = blockIdx.x * blockDim.x + threadIdx.x;
    if (e >= E) return;
    atomicAdd(&deg[edge[E + e]], 1);   // dst row
}

// ---- hierarchical scan: phase 1 — per-block (256 elems) inclusive scan + block sums
__global__ __launch_bounds__(256) void scan1_kernel(const int* __restrict__ deg,
                                                    int* __restrict__ scanned,
                                                    int* __restrict__ bsum, int n) {
    __shared__ int wsum[4];
    const int i    = blockIdx.x * 256 + threadIdx.x;
    const int lane = threadIdx.x & 63;
    const int w    = threadIdx.x >> 6;
    int v = (i < n) ? deg[i] : 0;
    int incl = v;
    #pragma unroll
    for (int s = 1; s < 64; s <<= 1) {
        int t = __shfl_up(incl, s, 64);
        if (lane >= s) incl += t;
    }
    if (lane == 63) wsum[w] = incl;
    __syncthreads();
    int add = 0;
    #pragma unroll
    for (int k = 0; k < 4; ++k) if (k < w) add += wsum[k];
    incl += add;
    if (i < n) scanned[i] = incl;
    if (threadIdx.x == 255) bsum[blockIdx.x] = incl;
}

// ---- phase 2 — single wave scans the block sums (nb ~ 196) → exclusive offsets
__global__ void scan2_kernel(const int* __restrict__ bsum, int* __restrict__ boff, int nb) {
    const int lane = threadIdx.x;
    int carry = 0;
    for (int base = 0; base < nb; base += 64) {
        int i = base + lane;
        int v = (i < nb) ? bsum[i] : 0;
        int incl = v;
        #pragma unroll
        for (int s = 1; s < 64; s <<= 1) {
            int t = __shfl_up(incl, s, 64);
            if (lane >= s) incl += t;
        }
        if (i < nb) boff[i] = carry + incl - v;
        carry += __shfl(incl, 63, 64);
    }
}

// ---- phase 3 — combine
__global__ __launch_bounds__(256) void scan3_kernel(const int* __restrict__ scanned,
                                                    const int* __restrict__ boff,
                                                    const int* __restrict__ deg,
                                                    int* __restrict__ off,
                                                    int* __restrict__ cursor, int n) {
    const int i = blockIdx.x * 256 + threadIdx.x;
    if (i >= n) return;
    int e = scanned[i] + boff[blockIdx.x];
    off[i + 1] = e;
    cursor[i]  = e - deg[i];
    if (i == 0) off[0] = 0;
}

__global__ void fill_csr_kernel(const int* __restrict__ edge, int E,
                                int* __restrict__ cursor, int* __restrict__ csr_src) {
    int e = blockIdx.x * blockDim.x + threadIdx.x;
    if (e >= E) return;
    int dst = edge[E + e];
    int pos = atomicAdd(&cursor[dst], 1);
    csr_src[pos] = edge[e];   // store src node id
}

// ---------------- weights: combined [din][192] = [Wl | Wr | 0pad] ----------------

__global__ void build_wc_kernel(const float* __restrict__ Wl, const float* __restrict__ Wr,
                                float* __restrict__ Wc, int din) {
    int idx = blockIdx.x * blockDim.x + threadIdx.x;
    if (idx >= din * YS) return;
    int k = idx / YS, c = idx % YS;
    float v = 0.f;
    if (c < MD)            v = Wl[k * MD + c];
    else if (c < 2 * MD)   v = Wr[k * MD + (c - MD)];
    Wc[idx] = v;
}

// ---------------- GEMM: Y[N,192] = A[N,DIN] @ Wc[DIN,192]  (+bias on cols 88..175) ----------------
// block = 256 threads, tile = 64 rows x 192 cols, thread = 4 rows x 12 cols

template <int DIN>
__global__ __launch_bounds__(256) void gemm_kernel(const float* __restrict__ A,
                                                   const float* __restrict__ Wc,
                                                   const float* __restrict__ bias,
                                                   float* __restrict__ Y, int N) {
    __shared__ float w[64 * YS];   // 48 KiB
    const int tid  = threadIdx.x;
    const int col0 = (tid & 15) * 12;
    const int rbase = blockIdx.x * 64 + (tid >> 4) * 4;

    const float* a0 = A + (size_t)min(rbase + 0, N - 1) * DIN;
    const float* a1 = A + (size_t)min(rbase + 1, N - 1) * DIN;
    const float* a2 = A + (size_t)min(rbase + 2, N - 1) * DIN;
    const float* a3 = A + (size_t)min(rbase + 3, N - 1) * DIN;

    float acc[4][12];
    #pragma unroll
    for (int r = 0; r < 4; ++r)
        #pragma unroll
        for (int j = 0; j < 12; ++j) acc[r][j] = 0.f;

    for (int kc = 0; kc < DIN; kc += 64) {
        const int klen = (DIN - kc < 64) ? (DIN - kc) : 64;
        const int nf4 = klen * (YS / 4);
        const float4* src = (const float4*)(Wc + kc * YS);
        for (int i = tid; i < nf4; i += 256) ((float4*)w)[i] = src[i];
        __syncthreads();

        for (int k = 0; k < klen; ++k) {
            const float* wr = &w[k * YS + col0];
            float wv[12];
            *(float4*)&wv[0] = *(const float4*)(wr);
            *(float4*)&wv[4] = *(const float4*)(wr + 4);
            *(float4*)&wv[8] = *(const float4*)(wr + 8);
            const int kk = kc + k;
            float av[4] = { a0[kk], a1[kk], a2[kk], a3[kk] };
            #pragma unroll
            for (int r = 0; r < 4; ++r)
                #pragma unroll
                for (int j = 0; j < 12; ++j)
                    acc[r][j] = fmaf(av[r], wv[j], acc[r][j]);
        }
        __syncthreads();
    }

    #pragma unroll
    for (int r = 0; r < 4; ++r) {
        const int row = rbase + r;
        if (row >= N) continue;
        float outv[12];
        #pragma unroll
        for (int j = 0; j < 12; ++j) {
            const int c = col0 + j;
            float v = acc[r][j];
            if (c >= MD && c < 2 * MD) v += bias[c - MD];
            outv[j] = v;
        }
        float* yp = Y + (size_t)row * YS + col0;
        *(float4*)(yp)     = *(float4*)&outv[0];
        *(float4*)(yp + 4) = *(float4*)&outv[4];
        *(float4*)(yp + 8) = *(float4*)&outv[8];
    }
}

// ---------------- fused aggregate: h = relu( (sum_{src in N(n)} yl[src]) / max(deg,1) + yr[n] ) ----------------
// one thread per (node, feature)

__global__ void agg_kernel(const float* __restrict__ Y, const int* __restrict__ off,
                           const int* __restrict__ csr, float* __restrict__ h, int N) {
    int idx = blockIdx.x * blockDim.x + threadIdx.x;
    if (idx >= N * MD) return;
    int n = idx / MD;
    int f = idx - n * MD;
    int s = off[n], e = off[n + 1];
    float acc = 0.f;
    for (int i = s; i < e; ++i) {
        acc += Y[(size_t)csr[i] * YS + f];
    }
    float d = (float)((e - s) > 1 ? (e - s) : 1);
    float v = acc / d + Y[(size_t)n * YS + MD + f];
    h[(size_t)n * MD + f] = fmaxf(v, 0.f);
}

// ---------------- pooling ----------------

__global__ void gstarts_kernel(const int* __restrict__ batch, int* __restrict__ gstart, int n) {
    int i = blockIdx.x * blockDim.x + threadIdx.x;
    if (i >= n) return;
    int b = batch[i];
    int prev = (i == 0) ? -1 : batch[i - 1];
    for (int g = prev + 1; g <= b; ++g) gstart[g] = i;
    if (i == n - 1) {
        for (int g = b + 1; g <= NG; ++g) gstart[g] = n;
    }
}

__global__ void pool_kernel(const float* __restrict__ h, const int* __restrict__ gstart,
                            float* __restrict__ pooled) {
    int g = blockIdx.x;
    int f = threadIdx.x;
    if (f >= MD) return;
    int s = gstart[g], e = gstart[g + 1];
    float acc = 0.f;
    for (int n = s; n < e; ++n) acc += h[(size_t)n * MD + f];
    pooled[g * MD + f] = acc;
}

__global__ void final_kernel(const float* __restrict__ pooled, const float* __restrict__ Wlin,
                             const float* __restrict__ blin, float* __restrict__ out) {
    int idx = blockIdx.x * blockDim.x + threadIdx.x;
    if (idx >= NG * OD) return;
    int g = idx / OD, o = idx - (idx / OD) * OD;
    float acc = blin[o];
    for (int f = 0; f < MD; ++f)
        acc = fmaf(pooled[g * MD + f], Wlin[f * OD + o], acc);
    out[idx] = acc;
}

// ---------------- launch ----------------

extern "C" void kernel_launch(void* const* d_in, const int* in_sizes, int n_in,
                              void* d_out, int out_size, void* d_ws, size_t ws_size,
                              hipStream_t stream) {
    const float* x     = (const float*)d_in[0];
    const int*   edge  = (const int*)d_in[1];
    const int*   batch = (const int*)d_in[2];
    const float* W1l = (const float*)d_in[3];
    const float* W1r = (const float*)d_in[4];
    const float* b1  = (const float*)d_in[5];
    const float* W2l = (const float*)d_in[6];
    const float* W2r = (const float*)d_in[7];
    const float* b2  = (const float*)d_in[8];
    const float* W3l = (const float*)d_in[9];
    const float* W3r = (const float*)d_in[10];
    const float* b3  = (const float*)d_in[11];
    const float* Wlin = (const float*)d_in[12];
    const float* blin = (const float*)d_in[13];
    float* out = (float*)d_out;

    const int N = in_sizes[0] / CF;   // 50000
    const int E = in_sizes[1] / 2;    // 800000
    const int NB = (N + 255) / 256;   // scan blocks

    char* ws = (char*)d_ws;
    auto alloc = [&](size_t bytes) -> void* {
        void* p = (void*)ws;
        ws += (bytes + 255) & ~(size_t)255;
        return p;
    };
    int*   deg     = (int*)alloc((size_t)N * 4);
    int*   off     = (int*)alloc((size_t)(N + 1) * 4);
    int*   cursor  = (int*)alloc((size_t)N * 4);
    int*   scanned = (int*)alloc((size_t)N * 4);
    int*   bsum    = (int*)alloc((size_t)NB * 4);
    int*   boff    = (int*)alloc((size_t)NB * 4);
    int*   csr     = (int*)alloc((size_t)E * 4);
    int*   gstart  = (int*)alloc((size_t)(NG + 1) * 4);
    float* Wc      = (float*)alloc((size_t)CF * YS * 4);
    float* Y       = (float*)alloc((size_t)N * YS * 4);
    float* h       = (float*)alloc((size_t)N * MD * 4);
    float* pooled  = (float*)alloc((size_t)NG * MD * 4);

    hipMemsetAsync(deg, 0, (size_t)N * 4, stream);
    count_deg_kernel<<<(E + 255) / 256, 256, 0, stream>>>(edge, E, deg);
    scan1_kernel<<<NB, 256, 0, stream>>>(deg, scanned, bsum, N);
    scan2_kernel<<<1, 64, 0, stream>>>(bsum, boff, NB);
    scan3_kernel<<<NB, 256, 0, stream>>>(scanned, boff, deg, off, cursor, N);
    fill_csr_kernel<<<(E + 255) / 256, 256, 0, stream>>>(edge, E, cursor, csr);

    const int gemm_blocks = (N + 63) / 64;
    const int agg_blocks  = (N * MD + 255) / 256;

    // layer 1
    build_wc_kernel<<<(CF * YS + 255) / 256, 256, 0, stream>>>(W1l, W1r, Wc, CF);
    gemm_kernel<CF><<<gemm_blocks, 256, 0, stream>>>(x, Wc, b1, Y, N);
    agg_kernel<<<agg_blocks, 256, 0, stream>>>(Y, off, csr, h, N);

    // layer 2
    build_wc_kernel<<<(MD * YS + 255) / 256, 256, 0, stream>>>(W2l, W2r, Wc, MD);
    gemm_kernel<MD><<<gemm_blocks, 256, 0, stream>>>(h, Wc, b2, Y, N);
    agg_kernel<<<agg_blocks, 256, 0, stream>>>(Y, off, csr, h, N);

    // layer 3
    build_wc_kernel<<<(MD * YS + 255) / 256, 256, 0, stream>>>(W3l, W3r, Wc, MD);
    gemm_kernel<MD><<<gemm_blocks, 256, 0, stream>>>(h, Wc, b3, Y, N);
    agg_kernel<<<agg_blocks, 256, 0, stream>>>(Y, off, csr, h, N);

    // pool + classifier
    gstarts_kernel<<<(N + 255) / 256, 256, 0, stream>>>(batch, gstart, N);
    pool_kernel<<<NG, 128, 0, stream>>>(h, gstart, pooled);
    final_kernel<<<(NG * OD + 255) / 256, 256, 0, stream>>>(pooled, Wlin, blin, out);
}

// Round 3
// 482.858 us; speedup vs baseline: 2.1515x; 1.3818x over previous
//
#include <hip/hip_runtime.h>
#include <hip/hip_fp16.h>

#define NN 50000
#define NG 256
#define CF 108
#define MD 88
#define OD 100
#define YS 192   // Y row stride in HALFS: [0,88)=yl, [88,176)=yr(+bias), [176,192) pad
#define H2S 96   // Y row stride in half2
#define F2 44    // half2 per 88-feat row

// ---------------- CSR build ----------------

__global__ void count_deg_kernel(const int* __restrict__ edge, int E, int* __restrict__ deg) {
    int e = blockIdx.x * blockDim.x + threadIdx.x;
    if (e >= E) return;
    atomicAdd(&deg[edge[E + e]], 1);   // dst row
}

__global__ __launch_bounds__(256) void scan1_kernel(const int* __restrict__ deg,
                                                    int* __restrict__ scanned,
                                                    int* __restrict__ bsum, int n) {
    __shared__ int wsum[4];
    const int i    = blockIdx.x * 256 + threadIdx.x;
    const int lane = threadIdx.x & 63;
    const int w    = threadIdx.x >> 6;
    int v = (i < n) ? deg[i] : 0;
    int incl = v;
    #pragma unroll
    for (int s = 1; s < 64; s <<= 1) {
        int t = __shfl_up(incl, s, 64);
        if (lane >= s) incl += t;
    }
    if (lane == 63) wsum[w] = incl;
    __syncthreads();
    int add = 0;
    #pragma unroll
    for (int k = 0; k < 4; ++k) if (k < w) add += wsum[k];
    incl += add;
    if (i < n) scanned[i] = incl;
    if (threadIdx.x == 255) bsum[blockIdx.x] = incl;
}

__global__ void scan2_kernel(const int* __restrict__ bsum, int* __restrict__ boff, int nb) {
    const int lane = threadIdx.x;
    int carry = 0;
    for (int base = 0; base < nb; base += 64) {
        int i = base + lane;
        int v = (i < nb) ? bsum[i] : 0;
        int incl = v;
        #pragma unroll
        for (int s = 1; s < 64; s <<= 1) {
            int t = __shfl_up(incl, s, 64);
            if (lane >= s) incl += t;
        }
        if (i < nb) boff[i] = carry + incl - v;
        carry += __shfl(incl, 63, 64);
    }
}

__global__ __launch_bounds__(256) void scan3_kernel(const int* __restrict__ scanned,
                                                    const int* __restrict__ boff,
                                                    const int* __restrict__ deg,
                                                    int* __restrict__ off,
                                                    int* __restrict__ cursor, int n) {
    const int i = blockIdx.x * 256 + threadIdx.x;
    if (i >= n) return;
    int e = scanned[i] + boff[blockIdx.x];
    off[i + 1] = e;
    cursor[i]  = e - deg[i];
    if (i == 0) off[0] = 0;
}

__global__ void fill_csr_kernel(const int* __restrict__ edge, int E,
                                int* __restrict__ cursor, int* __restrict__ csr_src) {
    int e = blockIdx.x * blockDim.x + threadIdx.x;
    if (e >= E) return;
    int dst = edge[E + e];
    int pos = atomicAdd(&cursor[dst], 1);
    csr_src[pos] = edge[e];   // store src node id
}

// ---------------- weights: combined [din][192] = [Wl | Wr | 0pad] ----------------

__global__ void build_wc_kernel(const float* __restrict__ Wl, const float* __restrict__ Wr,
                                float* __restrict__ Wc, int din) {
    int idx = blockIdx.x * blockDim.x + threadIdx.x;
    if (idx >= din * YS) return;
    int k = idx / YS, c = idx % YS;
    float v = 0.f;
    if (c < MD)            v = Wl[k * MD + c];
    else if (c < 2 * MD)   v = Wr[k * MD + (c - MD)];
    Wc[idx] = v;
}

// ---------------- GEMM: Y[N,192](half) = A[N,DIN] @ Wc[DIN,192]  (+bias on cols 88..175) ----

template <int DIN>
__global__ __launch_bounds__(256) void gemm_kernel(const float* __restrict__ A,
                                                   const float* __restrict__ Wc,
                                                   const float* __restrict__ bias,
                                                   __half* __restrict__ Y, int N) {
    __shared__ float w[64 * YS];   // 48 KiB
    const int tid  = threadIdx.x;
    const int col0 = (tid & 15) * 12;
    const int rbase = blockIdx.x * 64 + (tid >> 4) * 4;

    const float* a0 = A + (size_t)min(rbase + 0, N - 1) * DIN;
    const float* a1 = A + (size_t)min(rbase + 1, N - 1) * DIN;
    const float* a2 = A + (size_t)min(rbase + 2, N - 1) * DIN;
    const float* a3 = A + (size_t)min(rbase + 3, N - 1) * DIN;

    float acc[4][12];
    #pragma unroll
    for (int r = 0; r < 4; ++r)
        #pragma unroll
        for (int j = 0; j < 12; ++j) acc[r][j] = 0.f;

    for (int kc = 0; kc < DIN; kc += 64) {
        const int klen = (DIN - kc < 64) ? (DIN - kc) : 64;
        const int nf4 = klen * (YS / 4);
        const float4* src = (const float4*)(Wc + kc * YS);
        for (int i = tid; i < nf4; i += 256) ((float4*)w)[i] = src[i];
        __syncthreads();

        for (int k = 0; k < klen; ++k) {
            const float* wr = &w[k * YS + col0];
            float wv[12];
            *(float4*)&wv[0] = *(const float4*)(wr);
            *(float4*)&wv[4] = *(const float4*)(wr + 4);
            *(float4*)&wv[8] = *(const float4*)(wr + 8);
            const int kk = kc + k;
            float av[4] = { a0[kk], a1[kk], a2[kk], a3[kk] };
            #pragma unroll
            for (int r = 0; r < 4; ++r)
                #pragma unroll
                for (int j = 0; j < 12; ++j)
                    acc[r][j] = fmaf(av[r], wv[j], acc[r][j]);
        }
        __syncthreads();
    }

    #pragma unroll
    for (int r = 0; r < 4; ++r) {
        const int row = rbase + r;
        if (row >= N) continue;
        __half* yp = Y + (size_t)row * YS + col0;
        #pragma unroll
        for (int j = 0; j < 12; j += 2) {
            const int c = col0 + j;
            float v0 = acc[r][j], v1 = acc[r][j + 1];
            if (c >= MD && c < 2 * MD)     v0 += bias[c - MD];
            if (c + 1 >= MD && c + 1 < 2 * MD) v1 += bias[c + 1 - MD];
            *(__half2*)(yp + j) = __floats2half2_rn(v0, v1);
        }
    }
}

// ---------------- fused aggregate (half2 gather, fp32 accumulate) ----------------
// one thread per (node, feature-pair): idx = n*44 + fp

__global__ void agg_kernel(const __half2* __restrict__ Y2, const int* __restrict__ off,
                           const int* __restrict__ csr, float* __restrict__ h, int N) {
    int idx = blockIdx.x * blockDim.x + threadIdx.x;
    if (idx >= N * F2) return;
    int n  = idx / F2;
    int fp = idx - n * F2;
    int s = off[n], e = off[n + 1];
    float ax0 = 0.f, ay0 = 0.f, ax1 = 0.f, ay1 = 0.f;
    int i = s;
    for (; i + 1 < e; i += 2) {
        __half2 v0 = Y2[(size_t)csr[i]     * H2S + fp];
        __half2 v1 = Y2[(size_t)csr[i + 1] * H2S + fp];
        ax0 += __low2float(v0); ay0 += __high2float(v0);
        ax1 += __low2float(v1); ay1 += __high2float(v1);
    }
    if (i < e) {
        __half2 v0 = Y2[(size_t)csr[i] * H2S + fp];
        ax0 += __low2float(v0); ay0 += __high2float(v0);
    }
    float d = (float)((e - s) > 1 ? (e - s) : 1);
    float inv = 1.0f / d;
    __half2 r2 = Y2[(size_t)n * H2S + F2 + fp];   // yr
    float2 out;
    out.x = fmaxf((ax0 + ax1) * inv + __low2float(r2), 0.f);
    out.y = fmaxf((ay0 + ay1) * inv + __high2float(r2), 0.f);
    ((float2*)h)[(size_t)n * F2 + fp] = out;
}

// ---------------- pooling ----------------

__global__ void gstarts_kernel(const int* __restrict__ batch, int* __restrict__ gstart, int n) {
    int i = blockIdx.x * blockDim.x + threadIdx.x;
    if (i >= n) return;
    int b = batch[i];
    int prev = (i == 0) ? -1 : batch[i - 1];
    for (int g = prev + 1; g <= b; ++g) gstart[g] = i;
    if (i == n - 1) {
        for (int g = b + 1; g <= NG; ++g) gstart[g] = n;
    }
}

__global__ void pool_kernel(const float* __restrict__ h, const int* __restrict__ gstart,
                            float* __restrict__ pooled) {
    int g = blockIdx.x;
    int f = threadIdx.x;
    if (f >= MD) return;
    int s = gstart[g], e = gstart[g + 1];
    float acc = 0.f;
    for (int n = s; n < e; ++n) acc += h[(size_t)n * MD + f];
    pooled[g * MD + f] = acc;
}

__global__ void final_kernel(const float* __restrict__ pooled, const float* __restrict__ Wlin,
                             const float* __restrict__ blin, float* __restrict__ out) {
    int idx = blockIdx.x * blockDim.x + threadIdx.x;
    if (idx >= NG * OD) return;
    int g = idx / OD, o = idx - (idx / OD) * OD;
    float acc = blin[o];
    for (int f = 0; f < MD; ++f)
        acc = fmaf(pooled[g * MD + f], Wlin[f * OD + o], acc);
    out[idx] = acc;
}

// ---------------- launch ----------------

extern "C" void kernel_launch(void* const* d_in, const int* in_sizes, int n_in,
                              void* d_out, int out_size, void* d_ws, size_t ws_size,
                              hipStream_t stream) {
    const float* x     = (const float*)d_in[0];
    const int*   edge  = (const int*)d_in[1];
    const int*   batch = (const int*)d_in[2];
    const float* W1l = (const float*)d_in[3];
    const float* W1r = (const float*)d_in[4];
    const float* b1  = (const float*)d_in[5];
    const float* W2l = (const float*)d_in[6];
    const float* W2r = (const float*)d_in[7];
    const float* b2  = (const float*)d_in[8];
    const float* W3l = (const float*)d_in[9];
    const float* W3r = (const float*)d_in[10];
    const float* b3  = (const float*)d_in[11];
    const float* Wlin = (const float*)d_in[12];
    const float* blin = (const float*)d_in[13];
    float* out = (float*)d_out;

    const int N = in_sizes[0] / CF;   // 50000
    const int E = in_sizes[1] / 2;    // 800000
    const int NB = (N + 255) / 256;   // scan blocks

    char* ws = (char*)d_ws;
    auto alloc = [&](size_t bytes) -> void* {
        void* p = (void*)ws;
        ws += (bytes + 255) & ~(size_t)255;
        return p;
    };
    int*    deg     = (int*)alloc((size_t)N * 4);
    int*    off     = (int*)alloc((size_t)(N + 1) * 4);
    int*    cursor  = (int*)alloc((size_t)N * 4);
    int*    scanned = (int*)alloc((size_t)N * 4);
    int*    bsum    = (int*)alloc((size_t)NB * 4);
    int*    boff    = (int*)alloc((size_t)NB * 4);
    int*    csr     = (int*)alloc((size_t)E * 4);
    int*    gstart  = (int*)alloc((size_t)(NG + 1) * 4);
    float*  Wc      = (float*)alloc((size_t)CF * YS * 4);
    __half* Y       = (__half*)alloc((size_t)N * YS * 2);
    float*  h       = (float*)alloc((size_t)N * MD * 4);
    float*  pooled  = (float*)alloc((size_t)NG * MD * 4);

    hipMemsetAsync(deg, 0, (size_t)N * 4, stream);
    count_deg_kernel<<<(E + 255) / 256, 256, 0, stream>>>(edge, E, deg);
    scan1_kernel<<<NB, 256, 0, stream>>>(deg, scanned, bsum, N);
    scan2_kernel<<<1, 64, 0, stream>>>(bsum, boff, NB);
    scan3_kernel<<<NB, 256, 0, stream>>>(scanned, boff, deg, off, cursor, N);
    fill_csr_kernel<<<(E + 255) / 256, 256, 0, stream>>>(edge, E, cursor, csr);

    const int gemm_blocks = (N + 63) / 64;
    const int agg_blocks  = (N * F2 + 255) / 256;

    // layer 1
    build_wc_kernel<<<(CF * YS + 255) / 256, 256, 0, stream>>>(W1l, W1r, Wc, CF);
    gemm_kernel<CF><<<gemm_blocks, 256, 0, stream>>>(x, Wc, b1, Y, N);
    agg_kernel<<<agg_blocks, 256, 0, stream>>>((const __half2*)Y, off, csr, h, N);

    // layer 2
    build_wc_kernel<<<(MD * YS + 255) / 256, 256, 0, stream>>>(W2l, W2r, Wc, MD);
    gemm_kernel<MD><<<gemm_blocks, 256, 0, stream>>>(h, Wc, b2, Y, N);
    agg_kernel<<<agg_blocks, 256, 0, stream>>>((const __half2*)Y, off, csr, h, N);

    // layer 3
    build_wc_kernel<<<(MD * YS + 255) / 256, 256, 0, stream>>>(W3l, W3r, Wc, MD);
    gemm_kernel<MD><<<gemm_blocks, 256, 0, stream>>>(h, Wc, b3, Y, N);
    agg_kernel<<<agg_blocks, 256, 0, stream>>>((const __half2*)Y, off, csr, h, N);

    // pool + classifier
    gstarts_kernel<<<(N + 255) / 256, 256, 0, stream>>>(batch, gstart, N);
    pool_kernel<<<NG, 128, 0, stream>>>(h, gstart, pooled);
    final_kernel<<<(NG * OD + 255) / 256, 256, 0, stream>>>(pooled, Wlin, blin, out);
}

// Round 4
// 458.386 us; speedup vs baseline: 2.2664x; 1.0534x over previous
//
#include <hip/hip_runtime.h>
#include <hip/hip_fp16.h>

#define NN 50000
#define NG 256
#define CF 108
#define MD 88
#define OD 100
#define YS 192   // Y row stride in HALFS: [0,88)=yl, [88,176)=yr(+bias), [176,192) pad
#define H2S 96   // Y row stride in half2
#define F2 44    // half2 per 88-feat row

// ---------------- CSR build ----------------

__global__ void count_deg_kernel(const int* __restrict__ edge, int E, int* __restrict__ deg) {
    int e = blockIdx.x * blockDim.x + threadIdx.x;
    if (e >= E) return;
    atomicAdd(&deg[edge[E + e]], 1);   // dst row
}

__global__ __launch_bounds__(256) void scan1_kernel(const int* __restrict__ deg,
                                                    int* __restrict__ scanned,
                                                    int* __restrict__ bsum, int n) {
    __shared__ int wsum[4];
    const int i    = blockIdx.x * 256 + threadIdx.x;
    const int lane = threadIdx.x & 63;
    const int w    = threadIdx.x >> 6;
    int v = (i < n) ? deg[i] : 0;
    int incl = v;
    #pragma unroll
    for (int s = 1; s < 64; s <<= 1) {
        int t = __shfl_up(incl, s, 64);
        if (lane >= s) incl += t;
    }
    if (lane == 63) wsum[w] = incl;
    __syncthreads();
    int add = 0;
    #pragma unroll
    for (int k = 0; k < 4; ++k) if (k < w) add += wsum[k];
    incl += add;
    if (i < n) scanned[i] = incl;
    if (threadIdx.x == 255) bsum[blockIdx.x] = incl;
}

__global__ void scan2_kernel(const int* __restrict__ bsum, int* __restrict__ boff, int nb) {
    const int lane = threadIdx.x;
    int carry = 0;
    for (int base = 0; base < nb; base += 64) {
        int i = base + lane;
        int v = (i < nb) ? bsum[i] : 0;
        int incl = v;
        #pragma unroll
        for (int s = 1; s < 64; s <<= 1) {
            int t = __shfl_up(incl, s, 64);
            if (lane >= s) incl += t;
        }
        if (i < nb) boff[i] = carry + incl - v;
        carry += __shfl(incl, 63, 64);
    }
}

__global__ __launch_bounds__(256) void scan3_kernel(const int* __restrict__ scanned,
                                                    const int* __restrict__ boff,
                                                    const int* __restrict__ deg,
                                                    int* __restrict__ off,
                                                    int* __restrict__ cursor, int n) {
    const int i = blockIdx.x * 256 + threadIdx.x;
    if (i >= n) return;
    int e = scanned[i] + boff[blockIdx.x];
    off[i + 1] = e;
    cursor[i]  = e - deg[i];
    if (i == 0) off[0] = 0;
}

__global__ void fill_csr_kernel(const int* __restrict__ edge, int E,
                                int* __restrict__ cursor, int* __restrict__ csr_src) {
    int e = blockIdx.x * blockDim.x + threadIdx.x;
    if (e >= E) return;
    int dst = edge[E + e];
    int pos = atomicAdd(&cursor[dst], 1);
    csr_src[pos] = edge[e];   // store src node id
}

// ---------------- weights: combined [din][192] = [Wl | Wr | 0pad] ----------------

__global__ void build_wc_kernel(const float* __restrict__ Wl, const float* __restrict__ Wr,
                                float* __restrict__ Wc, int din) {
    int idx = blockIdx.x * blockDim.x + threadIdx.x;
    if (idx >= din * YS) return;
    int k = idx / YS, c = idx % YS;
    float v = 0.f;
    if (c < MD)            v = Wl[k * MD + c];
    else if (c < 2 * MD)   v = Wr[k * MD + (c - MD)];
    Wc[idx] = v;
}

// ---------------- GEMM: Y[N,192](half) = A[N,DIN] @ Wc[DIN,192]  (+bias on cols 88..175) ----
// block = 256 threads, tile = 64 rows x 192 cols, thread = 4 rows x 12 cols
// K processed in compile-time chunks of <=32 staged in 24KB LDS.

template <int KLEN>
__device__ __forceinline__ void gemm_chunk(const float* __restrict__ Wsrc, float* __restrict__ w,
                                           const float* a0, const float* a1,
                                           const float* a2, const float* a3, int kk0,
                                           int tid, int col0, float acc[4][12]) {
    const int nf4 = KLEN * (YS / 4);
    #pragma unroll
    for (int i = 0; i < (nf4 + 255) / 256; ++i) {
        int idx = tid + i * 256;
        if (nf4 % 256 == 0 || idx < nf4) ((float4*)w)[idx] = ((const float4*)Wsrc)[idx];
    }
    __syncthreads();

    #pragma unroll 4
    for (int k4 = 0; k4 < KLEN; k4 += 4) {
        float4 av0 = *(const float4*)(a0 + kk0 + k4);
        float4 av1 = *(const float4*)(a1 + kk0 + k4);
        float4 av2 = *(const float4*)(a2 + kk0 + k4);
        float4 av3 = *(const float4*)(a3 + kk0 + k4);
        #pragma unroll
        for (int kk = 0; kk < 4; ++kk) {
            const float* wr = &w[(k4 + kk) * YS + col0];
            float wv[12];
            *(float4*)&wv[0] = *(const float4*)(wr);
            *(float4*)&wv[4] = *(const float4*)(wr + 4);
            *(float4*)&wv[8] = *(const float4*)(wr + 8);
            float a[4] = { (&av0.x)[kk], (&av1.x)[kk], (&av2.x)[kk], (&av3.x)[kk] };
            #pragma unroll
            for (int r = 0; r < 4; ++r)
                #pragma unroll
                for (int j = 0; j < 12; ++j)
                    acc[r][j] = fmaf(a[r], wv[j], acc[r][j]);
        }
    }
    __syncthreads();
}

template <int DIN>
__global__ __launch_bounds__(256) void gemm_kernel(const float* __restrict__ A,
                                                   const float* __restrict__ Wc,
                                                   const float* __restrict__ bias,
                                                   __half* __restrict__ Y, int N) {
    __shared__ float w[32 * YS];   // 24 KiB
    const int tid  = threadIdx.x;
    const int col0 = (tid & 15) * 12;
    const int rbase = blockIdx.x * 64 + (tid >> 4) * 4;

    const float* a0 = A + (size_t)min(rbase + 0, N - 1) * DIN;
    const float* a1 = A + (size_t)min(rbase + 1, N - 1) * DIN;
    const float* a2 = A + (size_t)min(rbase + 2, N - 1) * DIN;
    const float* a3 = A + (size_t)min(rbase + 3, N - 1) * DIN;

    float acc[4][12];
    #pragma unroll
    for (int r = 0; r < 4; ++r)
        #pragma unroll
        for (int j = 0; j < 12; ++j) acc[r][j] = 0.f;

    if (DIN == 108) {
        gemm_chunk<32>(Wc +  0 * YS, w, a0, a1, a2, a3,  0, tid, col0, acc);
        gemm_chunk<32>(Wc + 32 * YS, w, a0, a1, a2, a3, 32, tid, col0, acc);
        gemm_chunk<32>(Wc + 64 * YS, w, a0, a1, a2, a3, 64, tid, col0, acc);
        gemm_chunk<12>(Wc + 96 * YS, w, a0, a1, a2, a3, 96, tid, col0, acc);
    } else {  // 88
        gemm_chunk<32>(Wc +  0 * YS, w, a0, a1, a2, a3,  0, tid, col0, acc);
        gemm_chunk<32>(Wc + 32 * YS, w, a0, a1, a2, a3, 32, tid, col0, acc);
        gemm_chunk<24>(Wc + 64 * YS, w, a0, a1, a2, a3, 64, tid, col0, acc);
    }

    #pragma unroll
    for (int r = 0; r < 4; ++r) {
        const int row = rbase + r;
        if (row >= N) continue;
        __half* yp = Y + (size_t)row * YS + col0;
        #pragma unroll
        for (int j = 0; j < 12; j += 2) {
            const int c = col0 + j;
            float v0 = acc[r][j], v1 = acc[r][j + 1];
            if (c >= MD && c < 2 * MD)         v0 += bias[c - MD];
            if (c + 1 >= MD && c + 1 < 2 * MD) v1 += bias[c + 1 - MD];
            *(__half2*)(yp + j) = __floats2half2_rn(v0, v1);
        }
    }
}

// ---------------- fused aggregate (half2 gather, fp32 accumulate) ----------------
// one thread per (node, feature-pair): idx = n*44 + fp

__global__ void agg_kernel(const __half2* __restrict__ Y2, const int* __restrict__ off,
                           const int* __restrict__ csr, float* __restrict__ h, int N) {
    int idx = blockIdx.x * blockDim.x + threadIdx.x;
    if (idx >= N * F2) return;
    int n  = idx / F2;
    int fp = idx - n * F2;
    int s = off[n], e = off[n + 1];
    float ax0 = 0.f, ay0 = 0.f, ax1 = 0.f, ay1 = 0.f;
    int i = s;
    for (; i + 1 < e; i += 2) {
        __half2 v0 = Y2[(size_t)csr[i]     * H2S + fp];
        __half2 v1 = Y2[(size_t)csr[i + 1] * H2S + fp];
        ax0 += __low2float(v0); ay0 += __high2float(v0);
        ax1 += __low2float(v1); ay1 += __high2float(v1);
    }
    if (i < e) {
        __half2 v0 = Y2[(size_t)csr[i] * H2S + fp];
        ax0 += __low2float(v0); ay0 += __high2float(v0);
    }
    float d = (float)((e - s) > 1 ? (e - s) : 1);
    float inv = 1.0f / d;
    __half2 r2 = Y2[(size_t)n * H2S + F2 + fp];   // yr
    float2 out;
    out.x = fmaxf((ax0 + ax1) * inv + __low2float(r2), 0.f);
    out.y = fmaxf((ay0 + ay1) * inv + __high2float(r2), 0.f);
    ((float2*)h)[(size_t)n * F2 + fp] = out;
}

// ---------------- pooling ----------------

__global__ void gstarts_kernel(const int* __restrict__ batch, int* __restrict__ gstart, int n) {
    int i = blockIdx.x * blockDim.x + threadIdx.x;
    if (i >= n) return;
    int b = batch[i];
    int prev = (i == 0) ? -1 : batch[i - 1];
    for (int g = prev + 1; g <= b; ++g) gstart[g] = i;
    if (i == n - 1) {
        for (int g = b + 1; g <= NG; ++g) gstart[g] = n;
    }
}

__global__ void pool_kernel(const float* __restrict__ h, const int* __restrict__ gstart,
                            float* __restrict__ pooled) {
    int g = blockIdx.x;
    int f = threadIdx.x;
    if (f >= MD) return;
    int s = gstart[g], e = gstart[g + 1];
    float acc = 0.f;
    for (int n = s; n < e; ++n) acc += h[(size_t)n * MD + f];
    pooled[g * MD + f] = acc;
}

__global__ void final_kernel(const float* __restrict__ pooled, const float* __restrict__ Wlin,
                             const float* __restrict__ blin, float* __restrict__ out) {
    int idx = blockIdx.x * blockDim.x + threadIdx.x;
    if (idx >= NG * OD) return;
    int g = idx / OD, o = idx - (idx / OD) * OD;
    float acc = blin[o];
    for (int f = 0; f < MD; ++f)
        acc = fmaf(pooled[g * MD + f], Wlin[f * OD + o], acc);
    out[idx] = acc;
}

// ---------------- launch ----------------

extern "C" void kernel_launch(void* const* d_in, const int* in_sizes, int n_in,
                              void* d_out, int out_size, void* d_ws, size_t ws_size,
                              hipStream_t stream) {
    const float* x     = (const float*)d_in[0];
    const int*   edge  = (const int*)d_in[1];
    const int*   batch = (const int*)d_in[2];
    const float* W1l = (const float*)d_in[3];
    const float* W1r = (const float*)d_in[4];
    const float* b1  = (const float*)d_in[5];
    const float* W2l = (const float*)d_in[6];
    const float* W2r = (const float*)d_in[7];
    const float* b2  = (const float*)d_in[8];
    const float* W3l = (const float*)d_in[9];
    const float* W3r = (const float*)d_in[10];
    const float* b3  = (const float*)d_in[11];
    const float* Wlin = (const float*)d_in[12];
    const float* blin = (const float*)d_in[13];
    float* out = (float*)d_out;

    const int N = in_sizes[0] / CF;   // 50000
    const int E = in_sizes[1] / 2;    // 800000
    const int NB = (N + 255) / 256;   // scan blocks

    char* ws = (char*)d_ws;
    auto alloc = [&](size_t bytes) -> void* {
        void* p = (void*)ws;
        ws += (bytes + 255) & ~(size_t)255;
        return p;
    };
    int*    deg     = (int*)alloc((size_t)N * 4);
    int*    off     = (int*)alloc((size_t)(N + 1) * 4);
    int*    cursor  = (int*)alloc((size_t)N * 4);
    int*    scanned = (int*)alloc((size_t)N * 4);
    int*    bsum    = (int*)alloc((size_t)NB * 4);
    int*    boff    = (int*)alloc((size_t)NB * 4);
    int*    csr     = (int*)alloc((size_t)E * 4);
    int*    gstart  = (int*)alloc((size_t)(NG + 1) * 4);
    float*  Wc      = (float*)alloc((size_t)CF * YS * 4);
    __half* Y       = (__half*)alloc((size_t)N * YS * 2);
    float*  h       = (float*)alloc((size_t)N * MD * 4);
    float*  pooled  = (float*)alloc((size_t)NG * MD * 4);

    hipMemsetAsync(deg, 0, (size_t)N * 4, stream);
    count_deg_kernel<<<(E + 255) / 256, 256, 0, stream>>>(edge, E, deg);
    scan1_kernel<<<NB, 256, 0, stream>>>(deg, scanned, bsum, N);
    scan2_kernel<<<1, 64, 0, stream>>>(bsum, boff, NB);
    scan3_kernel<<<NB, 256, 0, stream>>>(scanned, boff, deg, off, cursor, N);
    fill_csr_kernel<<<(E + 255) / 256, 256, 0, stream>>>(edge, E, cursor, csr);

    const int gemm_blocks = (N + 63) / 64;
    const int agg_blocks  = (N * F2 + 255) / 256;

    // layer 1
    build_wc_kernel<<<(CF * YS + 255) / 256, 256, 0, stream>>>(W1l, W1r, Wc, CF);
    gemm_kernel<CF><<<gemm_blocks, 256, 0, stream>>>(x, Wc, b1, Y, N);
    agg_kernel<<<agg_blocks, 256, 0, stream>>>((const __half2*)Y, off, csr, h, N);

    // layer 2
    build_wc_kernel<<<(MD * YS + 255) / 256, 256, 0, stream>>>(W2l, W2r, Wc, MD);
    gemm_kernel<MD><<<gemm_blocks, 256, 0, stream>>>(h, Wc, b2, Y, N);
    agg_kernel<<<agg_blocks, 256, 0, stream>>>((const __half2*)Y, off, csr, h, N);

    // layer 3
    build_wc_kernel<<<(MD * YS + 255) / 256, 256, 0, stream>>>(W3l, W3r, Wc, MD);
    gemm_kernel<MD><<<gemm_blocks, 256, 0, stream>>>(h, Wc, b3, Y, N);
    agg_kernel<<<agg_blocks, 256, 0, stream>>>((const __half2*)Y, off, csr, h, N);

    // pool + classifier
    gstarts_kernel<<<(N + 255) / 256, 256, 0, stream>>>(batch, gstart, N);
    pool_kernel<<<NG, 128, 0, stream>>>(h, gstart, pooled);
    final_kernel<<<(NG * OD + 255) / 256, 256, 0, stream>>>(pooled, Wlin, blin, out);
}

// Round 5
// 386.102 us; speedup vs baseline: 2.6906x; 1.1872x over previous
//
#include <hip/hip_runtime.h>
#include <hip/hip_fp16.h>

#define NN 50000
#define NG 256
#define CF 108
#define MD 88
#define OD 100
#define YS 192   // Y row stride in halfs: [0,88)=yl, [88,176)=yr(+bias), [176,192) pad
#define H2S 96   // Y row stride in half2
#define F2 44    // half2 per 88-feat row
#define HP 96    // h row stride in halfs (88 + 8 zero pad)
#define HP2 48   // h row stride in half2
#define K1P 128  // layer-1 K padded (108 -> 128)

typedef _Float16 f16x8 __attribute__((ext_vector_type(8)));
typedef float f32x4 __attribute__((ext_vector_type(4)));

// ---------------- CSR build ----------------

__global__ void count_deg_kernel(const int* __restrict__ edge, int E, int* __restrict__ deg) {
    int e = blockIdx.x * blockDim.x + threadIdx.x;
    if (e >= E) return;
    atomicAdd(&deg[edge[E + e]], 1);   // dst row
}

__global__ __launch_bounds__(256) void scan1_kernel(const int* __restrict__ deg,
                                                    int* __restrict__ scanned,
                                                    int* __restrict__ bsum, int n) {
    __shared__ int wsum[4];
    const int i    = blockIdx.x * 256 + threadIdx.x;
    const int lane = threadIdx.x & 63;
    const int w    = threadIdx.x >> 6;
    int v = (i < n) ? deg[i] : 0;
    int incl = v;
    #pragma unroll
    for (int s = 1; s < 64; s <<= 1) {
        int t = __shfl_up(incl, s, 64);
        if (lane >= s) incl += t;
    }
    if (lane == 63) wsum[w] = incl;
    __syncthreads();
    int add = 0;
    #pragma unroll
    for (int k = 0; k < 4; ++k) if (k < w) add += wsum[k];
    incl += add;
    if (i < n) scanned[i] = incl;
    if (threadIdx.x == 255) bsum[blockIdx.x] = incl;
}

__global__ void scan2_kernel(const int* __restrict__ bsum, int* __restrict__ boff, int nb) {
    const int lane = threadIdx.x;
    int carry = 0;
    for (int base = 0; base < nb; base += 64) {
        int i = base + lane;
        int v = (i < nb) ? bsum[i] : 0;
        int incl = v;
        #pragma unroll
        for (int s = 1; s < 64; s <<= 1) {
            int t = __shfl_up(incl, s, 64);
            if (lane >= s) incl += t;
        }
        if (i < nb) boff[i] = carry + incl - v;
        carry += __shfl(incl, 63, 64);
    }
}

__global__ __launch_bounds__(256) void scan3_kernel(const int* __restrict__ scanned,
                                                    const int* __restrict__ boff,
                                                    const int* __restrict__ deg,
                                                    int* __restrict__ off,
                                                    int* __restrict__ cursor, int n) {
    const int i = blockIdx.x * 256 + threadIdx.x;
    if (i >= n) return;
    int e = scanned[i] + boff[blockIdx.x];
    off[i + 1] = e;
    cursor[i]  = e - deg[i];
    if (i == 0) off[0] = 0;
}

__global__ void fill_csr_kernel(const int* __restrict__ edge, int E,
                                int* __restrict__ cursor, int* __restrict__ csr_src) {
    int e = blockIdx.x * blockDim.x + threadIdx.x;
    if (e >= E) return;
    int dst = edge[E + e];
    int pos = atomicAdd(&cursor[dst], 1);
    csr_src[pos] = edge[e];   // store src node id
}

// ---------------- x -> f16 padded [N][128] ----------------

__global__ void convx_kernel(const float* __restrict__ x, _Float16* __restrict__ xh, int N) {
    int i = blockIdx.x * blockDim.x + threadIdx.x;
    if (i >= N * K1P) return;
    int n = i >> 7, k = i & (K1P - 1);
    xh[i] = (k < CF) ? (_Float16)x[n * CF + k] : (_Float16)0.f;
}

// ---------------- transposed combined weights: Wct[176][KPAD] f16 ----------------
// Wct[c][k] = c<88 ? Wl[k][c] : Wr[k][c-88]; zero for k >= K

__global__ void build_wct_kernel(const float* __restrict__ Wl, const float* __restrict__ Wr,
                                 _Float16* __restrict__ Wct, int K, int KPAD) {
    int idx = blockIdx.x * blockDim.x + threadIdx.x;
    if (idx >= 176 * KPAD) return;
    int c = idx / KPAD, k = idx - c * KPAD;
    float v = 0.f;
    if (k < K) v = (c < MD) ? Wl[k * MD + c] : Wr[k * MD + (c - MD)];
    Wct[idx] = (_Float16)v;
}

// ---------------- MFMA GEMM: Y[N,192](f16) = A[N,KPAD](f16) @ Wct^T  (+bias cols 88..175) ----
// block = 256 = 4 independent waves; wave handles 16 rows x 176 cols (11 tiles of 16x16)

template <int KPAD>
__global__ __launch_bounds__(256) void gemm_mfma_kernel(const _Float16* __restrict__ Ah,
                                                        const _Float16* __restrict__ Wct,
                                                        const float* __restrict__ bias,
                                                        _Float16* __restrict__ Y, int N) {
    const int wave = threadIdx.x >> 6;
    const int lane = threadIdx.x & 63;
    const int r16  = lane & 15;   // A row in tile / B-and-C col in tile
    const int kg   = lane >> 4;   // k-group (8 halfs each)
    const int rbase = blockIdx.x * 64 + wave * 16;

    const int arow = min(rbase + r16, N - 1);
    const _Float16* ap = Ah + (size_t)arow * KPAD + kg * 8;

    f32x4 acc[11];
    #pragma unroll
    for (int t = 0; t < 11; ++t) acc[t] = (f32x4){0.f, 0.f, 0.f, 0.f};

    #pragma unroll
    for (int ks = 0; ks < KPAD / 32; ++ks) {
        f16x8 af = *(const f16x8*)(ap + ks * 32);
        #pragma unroll
        for (int t = 0; t < 11; ++t) {
            const _Float16* bp = Wct + (size_t)(t * 16 + r16) * KPAD + ks * 32 + kg * 8;
            f16x8 bf = *(const f16x8*)bp;
            acc[t] = __builtin_amdgcn_mfma_f32_16x16x32_f16(af, bf, acc[t], 0, 0, 0);
        }
    }

    const int orow0 = rbase + kg * 4;
    #pragma unroll
    for (int t = 0; t < 11; ++t) {
        const int c = t * 16 + r16;
        const float bv = (c >= MD) ? bias[c - MD] : 0.f;
        #pragma unroll
        for (int r = 0; r < 4; ++r) {
            const int row = orow0 + r;
            if (row < N) Y[(size_t)row * YS + c] = (_Float16)(acc[t][r] + bv);
        }
    }
}

// ---------------- fused aggregate (half2 gather, fp32 accumulate) -> h f16 [N][96] ----------
// one thread per (node, half2-slot): idx = n*48 + fp; fp in [44,48) writes zero pad

__global__ void agg_kernel(const __half2* __restrict__ Y2, const int* __restrict__ off,
                           const int* __restrict__ csr, __half2* __restrict__ h2, int N) {
    int idx = blockIdx.x * blockDim.x + threadIdx.x;
    if (idx >= N * HP2) return;
    int n  = idx / HP2;
    int fp = idx - n * HP2;
    if (fp >= F2) { h2[idx] = __floats2half2_rn(0.f, 0.f); return; }
    int s = off[n], e = off[n + 1];
    float ax0 = 0.f, ay0 = 0.f, ax1 = 0.f, ay1 = 0.f;
    int i = s;
    for (; i + 1 < e; i += 2) {
        __half2 v0 = Y2[(size_t)csr[i]     * H2S + fp];
        __half2 v1 = Y2[(size_t)csr[i + 1] * H2S + fp];
        ax0 += __low2float(v0); ay0 += __high2float(v0);
        ax1 += __low2float(v1); ay1 += __high2float(v1);
    }
    if (i < e) {
        __half2 v0 = Y2[(size_t)csr[i] * H2S + fp];
        ax0 += __low2float(v0); ay0 += __high2float(v0);
    }
    float d = (float)((e - s) > 1 ? (e - s) : 1);
    float inv = 1.0f / d;
    __half2 r2 = Y2[(size_t)n * H2S + F2 + fp];   // yr
    float ox = fmaxf((ax0 + ax1) * inv + __low2float(r2), 0.f);
    float oy = fmaxf((ay0 + ay1) * inv + __high2float(r2), 0.f);
    h2[idx] = __floats2half2_rn(ox, oy);
}

// ---------------- pooling ----------------

__global__ void gstarts_kernel(const int* __restrict__ batch, int* __restrict__ gstart, int n) {
    int i = blockIdx.x * blockDim.x + threadIdx.x;
    if (i >= n) return;
    int b = batch[i];
    int prev = (i == 0) ? -1 : batch[i - 1];
    for (int g = prev + 1; g <= b; ++g) gstart[g] = i;
    if (i == n - 1) {
        for (int g = b + 1; g <= NG; ++g) gstart[g] = n;
    }
}

__global__ void pool_kernel(const _Float16* __restrict__ h, const int* __restrict__ gstart,
                            float* __restrict__ pooled) {
    int g = blockIdx.x;
    int f = threadIdx.x;
    if (f >= MD) return;
    int s = gstart[g], e = gstart[g + 1];
    float acc = 0.f;
    for (int n = s; n < e; ++n) acc += (float)h[(size_t)n * HP + f];
    pooled[g * MD + f] = acc;
}

__global__ void final_kernel(const float* __restrict__ pooled, const float* __restrict__ Wlin,
                             const float* __restrict__ blin, float* __restrict__ out) {
    int idx = blockIdx.x * blockDim.x + threadIdx.x;
    if (idx >= NG * OD) return;
    int g = idx / OD, o = idx - (idx / OD) * OD;
    float acc = blin[o];
    for (int f = 0; f < MD; ++f)
        acc = fmaf(pooled[g * MD + f], Wlin[f * OD + o], acc);
    out[idx] = acc;
}

// ---------------- launch ----------------

extern "C" void kernel_launch(void* const* d_in, const int* in_sizes, int n_in,
                              void* d_out, int out_size, void* d_ws, size_t ws_size,
                              hipStream_t stream) {
    const float* x     = (const float*)d_in[0];
    const int*   edge  = (const int*)d_in[1];
    const int*   batch = (const int*)d_in[2];
    const float* W1l = (const float*)d_in[3];
    const float* W1r = (const float*)d_in[4];
    const float* b1  = (const float*)d_in[5];
    const float* W2l = (const float*)d_in[6];
    const float* W2r = (const float*)d_in[7];
    const float* b2  = (const float*)d_in[8];
    const float* W3l = (const float*)d_in[9];
    const float* W3r = (const float*)d_in[10];
    const float* b3  = (const float*)d_in[11];
    const float* Wlin = (const float*)d_in[12];
    const float* blin = (const float*)d_in[13];
    float* out = (float*)d_out;

    const int N = in_sizes[0] / CF;   // 50000
    const int E = in_sizes[1] / 2;    // 800000
    const int NB = (N + 255) / 256;   // scan blocks

    char* ws = (char*)d_ws;
    auto alloc = [&](size_t bytes) -> void* {
        void* p = (void*)ws;
        ws += (bytes + 255) & ~(size_t)255;
        return p;
    };
    int*       deg     = (int*)alloc((size_t)N * 4);
    int*       off     = (int*)alloc((size_t)(N + 1) * 4);
    int*       cursor  = (int*)alloc((size_t)N * 4);
    int*       scanned = (int*)alloc((size_t)N * 4);
    int*       bsum    = (int*)alloc((size_t)NB * 4);
    int*       boff    = (int*)alloc((size_t)NB * 4);
    int*       csr     = (int*)alloc((size_t)E * 4);
    int*       gstart  = (int*)alloc((size_t)(NG + 1) * 4);
    _Float16*  Wct     = (_Float16*)alloc((size_t)176 * K1P * 2);
    _Float16*  xh      = (_Float16*)alloc((size_t)N * K1P * 2);
    _Float16*  Y       = (_Float16*)alloc((size_t)N * YS * 2);
    _Float16*  h       = (_Float16*)alloc((size_t)N * HP * 2);
    float*     pooled  = (float*)alloc((size_t)NG * MD * 4);

    hipMemsetAsync(deg, 0, (size_t)N * 4, stream);
    count_deg_kernel<<<(E + 255) / 256, 256, 0, stream>>>(edge, E, deg);
    scan1_kernel<<<NB, 256, 0, stream>>>(deg, scanned, bsum, N);
    scan2_kernel<<<1, 64, 0, stream>>>(bsum, boff, NB);
    scan3_kernel<<<NB, 256, 0, stream>>>(scanned, boff, deg, off, cursor, N);
    fill_csr_kernel<<<(E + 255) / 256, 256, 0, stream>>>(edge, E, cursor, csr);

    convx_kernel<<<(N * K1P + 255) / 256, 256, 0, stream>>>(x, xh, N);

    const int gemm_blocks = (N + 63) / 64;
    const int agg_blocks  = (N * HP2 + 255) / 256;

    // layer 1 (K=108, KPAD=128)
    build_wct_kernel<<<(176 * K1P + 255) / 256, 256, 0, stream>>>(W1l, W1r, Wct, CF, K1P);
    gemm_mfma_kernel<K1P><<<gemm_blocks, 256, 0, stream>>>(xh, Wct, b1, Y, N);
    agg_kernel<<<agg_blocks, 256, 0, stream>>>((const __half2*)Y, off, csr, (__half2*)h, N);

    // layer 2 (K=88, KPAD=96)
    build_wct_kernel<<<(176 * HP + 255) / 256, 256, 0, stream>>>(W2l, W2r, Wct, MD, HP);
    gemm_mfma_kernel<HP><<<gemm_blocks, 256, 0, stream>>>(h, Wct, b2, Y, N);
    agg_kernel<<<agg_blocks, 256, 0, stream>>>((const __half2*)Y, off, csr, (__half2*)h, N);

    // layer 3 (K=88, KPAD=96)
    build_wct_kernel<<<(176 * HP + 255) / 256, 256, 0, stream>>>(W3l, W3r, Wct, MD, HP);
    gemm_mfma_kernel<HP><<<gemm_blocks, 256, 0, stream>>>(h, Wct, b3, Y, N);
    agg_kernel<<<agg_blocks, 256, 0, stream>>>((const __half2*)Y, off, csr, (__half2*)h, N);

    // pool + classifier
    gstarts_kernel<<<(N + 255) / 256, 256, 0, stream>>>(batch, gstart, N);
    pool_kernel<<<NG, 128, 0, stream>>>(h, gstart, pooled);
    final_kernel<<<(NG * OD + 255) / 256, 256, 0, stream>>>(pooled, Wlin, blin, out);
}

// Round 6
// 334.540 us; speedup vs baseline: 3.1054x; 1.1541x over previous
//
#include <hip/hip_runtime.h>
#include <hip/hip_fp16.h>

#define NN 50000
#define NG 256
#define CF 108
#define MD 88
#define OD 100
#define F2 44    // half2 per 88-feat row
#define HP 96    // h row stride in halfs (88 + 8 zero pad, MFMA K=96)
#define HP2 48   // h row stride in half2
#define K1P 128  // layer-1 K padded (108 -> 128)

typedef _Float16 f16x8 __attribute__((ext_vector_type(8)));
typedef float f32x4 __attribute__((ext_vector_type(4)));

// ---------------- CSR build ----------------

__global__ void count_deg_kernel(const int* __restrict__ edge, int E, int* __restrict__ deg) {
    int e = blockIdx.x * blockDim.x + threadIdx.x;
    if (e >= E) return;
    atomicAdd(&deg[edge[E + e]], 1);   // dst row
}

__global__ __launch_bounds__(256) void scan1_kernel(const int* __restrict__ deg,
                                                    int* __restrict__ scanned,
                                                    int* __restrict__ bsum, int n) {
    __shared__ int wsum[4];
    const int i    = blockIdx.x * 256 + threadIdx.x;
    const int lane = threadIdx.x & 63;
    const int w    = threadIdx.x >> 6;
    int v = (i < n) ? deg[i] : 0;
    int incl = v;
    #pragma unroll
    for (int s = 1; s < 64; s <<= 1) {
        int t = __shfl_up(incl, s, 64);
        if (lane >= s) incl += t;
    }
    if (lane == 63) wsum[w] = incl;
    __syncthreads();
    int add = 0;
    #pragma unroll
    for (int k = 0; k < 4; ++k) if (k < w) add += wsum[k];
    incl += add;
    if (i < n) scanned[i] = incl;
    if (threadIdx.x == 255) bsum[blockIdx.x] = incl;
}

__global__ void scan2_kernel(const int* __restrict__ bsum, int* __restrict__ boff, int nb) {
    const int lane = threadIdx.x;
    int carry = 0;
    for (int base = 0; base < nb; base += 64) {
        int i = base + lane;
        int v = (i < nb) ? bsum[i] : 0;
        int incl = v;
        #pragma unroll
        for (int s = 1; s < 64; s <<= 1) {
            int t = __shfl_up(incl, s, 64);
            if (lane >= s) incl += t;
        }
        if (i < nb) boff[i] = carry + incl - v;
        carry += __shfl(incl, 63, 64);
    }
}

__global__ __launch_bounds__(256) void scan3_kernel(const int* __restrict__ scanned,
                                                    const int* __restrict__ boff,
                                                    const int* __restrict__ deg,
                                                    int* __restrict__ off,
                                                    int* __restrict__ cursor, int n) {
    const int i = blockIdx.x * 256 + threadIdx.x;
    if (i >= n) return;
    int e = scanned[i] + boff[blockIdx.x];
    off[i + 1] = e;
    cursor[i]  = e - deg[i];
    if (i == 0) off[0] = 0;
}

__global__ void fill_csr_kernel(const int* __restrict__ edge, int E,
                                int* __restrict__ cursor, int* __restrict__ csr_src) {
    int e = blockIdx.x * blockDim.x + threadIdx.x;
    if (e >= E) return;
    int dst = edge[E + e];
    int pos = atomicAdd(&cursor[dst], 1);
    csr_src[pos] = edge[e];   // store src node id
}

// ---------------- x -> f16 padded [N][128] ----------------

__global__ void convx_kernel(const float* __restrict__ x, _Float16* __restrict__ xh, int N) {
    int i = blockIdx.x * blockDim.x + threadIdx.x;
    if (i >= N * K1P) return;
    int n = i >> 7, k = i & (K1P - 1);
    xh[i] = (k < CF) ? (_Float16)x[n * CF + k] : (_Float16)0.f;
}

// ---------------- transposed combined weights: Wct[176][KPAD] f16 ----------------

__global__ void build_wct_kernel(const float* __restrict__ Wl, const float* __restrict__ Wr,
                                 _Float16* __restrict__ Wct, int K, int KPAD) {
    int idx = blockIdx.x * blockDim.x + threadIdx.x;
    if (idx >= 176 * KPAD) return;
    int c = idx / KPAD, k = idx - c * KPAD;
    float v = 0.f;
    if (k < K) v = (c < MD) ? Wl[k * MD + c] : Wr[k * MD + (c - MD)];
    Wct[idx] = (_Float16)v;
}

// ---------------- MFMA GEMM: yl[N,88] / yr[N,88] (f16) = A[N,KPAD] @ Wct^T ----------------
// block = 256 = 4 independent waves; wave: 16 rows x 176 cols (11 tiles of 16x16)
// cols 0..87 -> yl; cols 88..175 -> yr (+bias)

template <int KPAD>
__global__ __launch_bounds__(256) void gemm_mfma_kernel(const _Float16* __restrict__ Ah,
                                                        const _Float16* __restrict__ Wct,
                                                        const float* __restrict__ bias,
                                                        _Float16* __restrict__ yl,
                                                        _Float16* __restrict__ yr, int N) {
    const int wave = threadIdx.x >> 6;
    const int lane = threadIdx.x & 63;
    const int r16  = lane & 15;
    const int kg   = lane >> 4;
    const int rbase = blockIdx.x * 64 + wave * 16;

    const int arow = min(rbase + r16, N - 1);
    const _Float16* ap = Ah + (size_t)arow * KPAD + kg * 8;

    f32x4 acc[11];
    #pragma unroll
    for (int t = 0; t < 11; ++t) acc[t] = (f32x4){0.f, 0.f, 0.f, 0.f};

    #pragma unroll
    for (int ks = 0; ks < KPAD / 32; ++ks) {
        f16x8 af = *(const f16x8*)(ap + ks * 32);
        #pragma unroll
        for (int t = 0; t < 11; ++t) {
            const _Float16* bp = Wct + (size_t)(t * 16 + r16) * KPAD + ks * 32 + kg * 8;
            f16x8 bf = *(const f16x8*)bp;
            acc[t] = __builtin_amdgcn_mfma_f32_16x16x32_f16(af, bf, acc[t], 0, 0, 0);
        }
    }

    const int orow0 = rbase + kg * 4;
    #pragma unroll
    for (int t = 0; t < 11; ++t) {
        const int c = t * 16 + r16;
        const bool isr = (c >= MD);
        const float bv = isr ? bias[c - MD] : 0.f;
        _Float16* dst = isr ? (yr + (c - MD)) : (yl + c);
        #pragma unroll
        for (int r = 0; r < 4; ++r) {
            const int row = orow0 + r;
            if (row < N) dst[(size_t)row * MD] = (_Float16)(acc[t][r] + bv);
        }
    }
}

// ---------------- fused aggregate (compact yl gather, fp32 accumulate) -> h f16 [N][96] ----

__global__ void agg_kernel(const __half2* __restrict__ yl2, const __half2* __restrict__ yr2,
                           const int* __restrict__ off, const int* __restrict__ csr,
                           __half2* __restrict__ h2, int N) {
    int idx = blockIdx.x * blockDim.x + threadIdx.x;
    if (idx >= N * HP2) return;
    int n  = idx / HP2;
    int fp = idx - n * HP2;
    if (fp >= F2) { h2[idx] = __floats2half2_rn(0.f, 0.f); return; }
    int s = off[n], e = off[n + 1];
    float ax0 = 0.f, ay0 = 0.f, ax1 = 0.f, ay1 = 0.f;
    int i = s;
    for (; i + 1 < e; i += 2) {
        __half2 v0 = yl2[(size_t)csr[i]     * F2 + fp];
        __half2 v1 = yl2[(size_t)csr[i + 1] * F2 + fp];
        ax0 += __low2float(v0); ay0 += __high2float(v0);
        ax1 += __low2float(v1); ay1 += __high2float(v1);
    }
    if (i < e) {
        __half2 v0 = yl2[(size_t)csr[i] * F2 + fp];
        ax0 += __low2float(v0); ay0 += __high2float(v0);
    }
    float d = (float)((e - s) > 1 ? (e - s) : 1);
    float inv = 1.0f / d;
    __half2 r2 = yr2[(size_t)n * F2 + fp];
    float ox = fmaxf((ax0 + ax1) * inv + __low2float(r2), 0.f);
    float oy = fmaxf((ay0 + ay1) * inv + __high2float(r2), 0.f);
    h2[idx] = __floats2half2_rn(ox, oy);
}

// ---------------- pooling ----------------

__global__ void gstarts_kernel(const int* __restrict__ batch, int* __restrict__ gstart, int n) {
    int i = blockIdx.x * blockDim.x + threadIdx.x;
    if (i >= n) return;
    int b = batch[i];
    int prev = (i == 0) ? -1 : batch[i - 1];
    for (int g = prev + 1; g <= b; ++g) gstart[g] = i;
    if (i == n - 1) {
        for (int g = b + 1; g <= NG; ++g) gstart[g] = n;
    }
}

// block per graph; 4 waves stride nodes; lanes 0..43 hold a half2 feature pair
__global__ __launch_bounds__(256) void pool_kernel(const __half2* __restrict__ h2,
                                                   const int* __restrict__ gstart,
                                                   float* __restrict__ pooled) {
    __shared__ float red[4][F2][2];
    const int g    = blockIdx.x;
    const int w    = threadIdx.x >> 6;
    const int lane = threadIdx.x & 63;
    const int s = gstart[g], e = gstart[g + 1];

    float ax0 = 0.f, ay0 = 0.f, ax1 = 0.f, ay1 = 0.f;
    if (lane < F2) {
        int n = s + w;
        for (; n + 4 < e; n += 8) {
            __half2 v0 = h2[(size_t)n * HP2 + lane];
            __half2 v1 = h2[(size_t)(n + 4) * HP2 + lane];
            ax0 += __low2float(v0); ay0 += __high2float(v0);
            ax1 += __low2float(v1); ay1 += __high2float(v1);
        }
        if (n < e) {
            __half2 v0 = h2[(size_t)n * HP2 + lane];
            ax0 += __low2float(v0); ay0 += __high2float(v0);
        }
        red[w][lane][0] = ax0 + ax1;
        red[w][lane][1] = ay0 + ay1;
    }
    __syncthreads();
    if (threadIdx.x < F2) {
        const int fp = threadIdx.x;
        float sx = red[0][fp][0] + red[1][fp][0] + red[2][fp][0] + red[3][fp][0];
        float sy = red[0][fp][1] + red[1][fp][1] + red[2][fp][1] + red[3][fp][1];
        float2* pp = (float2*)(pooled + (size_t)g * MD);
        pp[fp] = make_float2(sx, sy);
    }
}

__global__ void final_kernel(const float* __restrict__ pooled, const float* __restrict__ Wlin,
                             const float* __restrict__ blin, float* __restrict__ out) {
    int idx = blockIdx.x * blockDim.x + threadIdx.x;
    if (idx >= NG * OD) return;
    int g = idx / OD, o = idx - (idx / OD) * OD;
    float acc = blin[o];
    for (int f = 0; f < MD; ++f)
        acc = fmaf(pooled[g * MD + f], Wlin[f * OD + o], acc);
    out[idx] = acc;
}

// ---------------- launch ----------------

extern "C" void kernel_launch(void* const* d_in, const int* in_sizes, int n_in,
                              void* d_out, int out_size, void* d_ws, size_t ws_size,
                              hipStream_t stream) {
    const float* x     = (const float*)d_in[0];
    const int*   edge  = (const int*)d_in[1];
    const int*   batch = (const int*)d_in[2];
    const float* W1l = (const float*)d_in[3];
    const float* W1r = (const float*)d_in[4];
    const float* b1  = (const float*)d_in[5];
    const float* W2l = (const float*)d_in[6];
    const float* W2r = (const float*)d_in[7];
    const float* b2  = (const float*)d_in[8];
    const float* W3l = (const float*)d_in[9];
    const float* W3r = (const float*)d_in[10];
    const float* b3  = (const float*)d_in[11];
    const float* Wlin = (const float*)d_in[12];
    const float* blin = (const float*)d_in[13];
    float* out = (float*)d_out;

    const int N = in_sizes[0] / CF;   // 50000
    const int E = in_sizes[1] / 2;    // 800000
    const int NB = (N + 255) / 256;   // scan blocks

    char* ws = (char*)d_ws;
    auto alloc = [&](size_t bytes) -> void* {
        void* p = (void*)ws;
        ws += (bytes + 255) & ~(size_t)255;
        return p;
    };
    int*       deg     = (int*)alloc((size_t)N * 4);
    int*       off     = (int*)alloc((size_t)(N + 1) * 4);
    int*       cursor  = (int*)alloc((size_t)N * 4);
    int*       scanned = (int*)alloc((size_t)N * 4);
    int*       bsum    = (int*)alloc((size_t)NB * 4);
    int*       boff    = (int*)alloc((size_t)NB * 4);
    int*       csr     = (int*)alloc((size_t)E * 4);
    int*       gstart  = (int*)alloc((size_t)(NG + 1) * 4);
    _Float16*  Wct     = (_Float16*)alloc((size_t)176 * K1P * 2);
    _Float16*  xh      = (_Float16*)alloc((size_t)N * K1P * 2);
    _Float16*  yl      = (_Float16*)alloc((size_t)N * MD * 2);
    _Float16*  yr      = (_Float16*)alloc((size_t)N * MD * 2);
    _Float16*  h       = (_Float16*)alloc((size_t)N * HP * 2);
    float*     pooled  = (float*)alloc((size_t)NG * MD * 4);

    hipMemsetAsync(deg, 0, (size_t)N * 4, stream);
    count_deg_kernel<<<(E + 255) / 256, 256, 0, stream>>>(edge, E, deg);
    scan1_kernel<<<NB, 256, 0, stream>>>(deg, scanned, bsum, N);
    scan2_kernel<<<1, 64, 0, stream>>>(bsum, boff, NB);
    scan3_kernel<<<NB, 256, 0, stream>>>(scanned, boff, deg, off, cursor, N);
    fill_csr_kernel<<<(E + 255) / 256, 256, 0, stream>>>(edge, E, cursor, csr);

    convx_kernel<<<(N * K1P + 255) / 256, 256, 0, stream>>>(x, xh, N);

    const int gemm_blocks = (N + 63) / 64;
    const int agg_blocks  = (N * HP2 + 255) / 256;

    // layer 1 (K=108, KPAD=128)
    build_wct_kernel<<<(176 * K1P + 255) / 256, 256, 0, stream>>>(W1l, W1r, Wct, CF, K1P);
    gemm_mfma_kernel<K1P><<<gemm_blocks, 256, 0, stream>>>(xh, Wct, b1, yl, yr, N);
    agg_kernel<<<agg_blocks, 256, 0, stream>>>((const __half2*)yl, (const __half2*)yr, off, csr, (__half2*)h, N);

    // layer 2 (K=88, KPAD=96)
    build_wct_kernel<<<(176 * HP + 255) / 256, 256, 0, stream>>>(W2l, W2r, Wct, MD, HP);
    gemm_mfma_kernel<HP><<<gemm_blocks, 256, 0, stream>>>(h, Wct, b2, yl, yr, N);
    agg_kernel<<<agg_blocks, 256, 0, stream>>>((const __half2*)yl, (const __half2*)yr, off, csr, (__half2*)h, N);

    // layer 3 (K=88, KPAD=96)
    build_wct_kernel<<<(176 * HP + 255) / 256, 256, 0, stream>>>(W3l, W3r, Wct, MD, HP);
    gemm_mfma_kernel<HP><<<gemm_blocks, 256, 0, stream>>>(h, Wct, b3, yl, yr, N);
    agg_kernel<<<agg_blocks, 256, 0, stream>>>((const __half2*)yl, (const __half2*)yr, off, csr, (__half2*)h, N);

    // pool + classifier
    gstarts_kernel<<<(N + 255) / 256, 256, 0, stream>>>(batch, gstart, N);
    pool_kernel<<<NG, 256, 0, stream>>>((const __half2*)h, gstart, pooled);
    final_kernel<<<(NG * OD + 255) / 256, 256, 0, stream>>>(pooled, Wlin, blin, out);
}